// Round 1
// baseline (361.964 us; speedup 1.0000x reference)
//
#include <hip/hip_runtime.h>
#include <hip/hip_bf16.h>

#define NTOK 4096   // B*T
#define DDIM 1024
#define NEXP 8
#define FDIM 2048
#define CAP  4096   // max assignments per expert

typedef float f32x4 __attribute__((ext_vector_type(4)));
typedef short s16x8 __attribute__((ext_vector_type(8)));

__device__ __forceinline__ unsigned short f2bf(float f) {
  unsigned int u = __float_as_uint(f);
  unsigned int r = u + 0x7fffu + ((u >> 16) & 1u);
  return (unsigned short)(r >> 16);
}

__device__ __forceinline__ void gload16(const void* g, void* l) {
  __builtin_amdgcn_global_load_lds(
      (__attribute__((address_space(1))) unsigned int*)(g),
      (__attribute__((address_space(3))) unsigned int*)(l), 16, 0, 0);
}

// ---------------- convert x fp32 -> bf16 ----------------
__global__ void k_convert_x(const float* __restrict__ x, unsigned short* __restrict__ xb) {
  int i = blockIdx.x * 256 + threadIdx.x;          // one thread per 8 elems
  const float4* x4 = (const float4*)x;
  float4 a = x4[2*i], b = x4[2*i+1];
  s16x8 o;
  o[0]=(short)f2bf(a.x); o[1]=(short)f2bf(a.y); o[2]=(short)f2bf(a.z); o[3]=(short)f2bf(a.w);
  o[4]=(short)f2bf(b.x); o[5]=(short)f2bf(b.y); o[6]=(short)f2bf(b.z); o[7]=(short)f2bf(b.w);
  ((s16x8*)xb)[i] = o;
}

// ---------------- transpose+cast weights: src [E][R][C] f32 -> dst [E][C][R] bf16 ----------------
__global__ void k_transpose_cast(const float* __restrict__ src, unsigned short* __restrict__ dst,
                                 int R, int C) {
  __shared__ float tile[32][33];
  int e = blockIdx.z;
  int c0 = blockIdx.x * 32, r0 = blockIdx.y * 32;
  const float* s = src + (size_t)e * R * C;
  unsigned short* d = dst + (size_t)e * R * C;
  int tx = threadIdx.x, ty = threadIdx.y;          // 32 x 8
  #pragma unroll
  for (int i = 0; i < 4; i++)
    tile[ty + i*8][tx] = s[(size_t)(r0 + ty + i*8) * C + (c0 + tx)];
  __syncthreads();
  #pragma unroll
  for (int i = 0; i < 4; i++)
    d[(size_t)(c0 + ty + i*8) * R + (r0 + tx)] = f2bf(tile[tx][ty + i*8]);
}

// ---------------- router: logits (fp64 acc), top-2, weights, aux stats, expert lists ----------------
__global__ void k_router(const float* __restrict__ x, const float* __restrict__ gw,
                         float* __restrict__ topw, int* __restrict__ elist,
                         int* __restrict__ ecnt, int* __restrict__ cnt1,
                         float* __restrict__ psum, float* __restrict__ sqsum) {
  __shared__ float bps[NEXP];
  __shared__ int bc[NEXP];
  __shared__ float bsq;
  int tid = threadIdx.x;
  if (tid < NEXP) { bps[tid] = 0.f; bc[tid] = 0; }
  if (tid == 0) bsq = 0.f;
  __syncthreads();
  int wv = tid >> 6, lane = tid & 63;
  int t = blockIdx.x * 4 + wv;                     // one wave per token
  double acc[NEXP];
  #pragma unroll
  for (int e = 0; e < NEXP; e++) acc[e] = 0.0;
  const float4* x4 = (const float4*)(x + (size_t)t * DDIM);
  for (int i = 0; i < 4; i++) {
    float4 xv = x4[i*64 + lane];
    int d0 = (i*64 + lane) * 4;
    float xs[4] = {xv.x, xv.y, xv.z, xv.w};
    #pragma unroll
    for (int j = 0; j < 4; j++) {
      double xd = (double)xs[j];
      #pragma unroll
      for (int e = 0; e < NEXP; e++)
        acc[e] += xd * (double)gw[(d0 + j) * NEXP + e];
    }
  }
  #pragma unroll
  for (int s = 32; s >= 1; s >>= 1) {
    #pragma unroll
    for (int e = 0; e < NEXP; e++)
      acc[e] += __shfl_xor(acc[e], s);
  }
  if (lane == 0) {
    int i0 = 0; double v0 = acc[0];
    #pragma unroll
    for (int e = 1; e < NEXP; e++) if (acc[e] > v0) { v0 = acc[e]; i0 = e; }
    int i1 = (i0 == 0) ? 1 : 0; double v1 = acc[i1];
    #pragma unroll
    for (int e = 0; e < NEXP; e++) if (e != i0 && acc[e] > v1) { v1 = acc[e]; i1 = e; }
    float w0 = 1.0f / (1.0f + expf((float)(v1 - v0)));   // softmax([v0,v1])[0]
    topw[2*t] = w0; topw[2*t + 1] = 1.0f - w0;
    int s0 = atomicAdd(&ecnt[i0], 1); elist[i0*CAP + s0] = 2*t;
    int s1 = atomicAdd(&ecnt[i1], 1); elist[i1*CAP + s1] = 2*t + 1;
    atomicAdd(&bc[i0], 1);
    float lm = (float)acc[0];
    #pragma unroll
    for (int e = 1; e < NEXP; e++) lm = fmaxf(lm, (float)acc[e]);
    float pe[NEXP], ps = 0.f, sq = 0.f;
    #pragma unroll
    for (int e = 0; e < NEXP; e++) {
      float le = (float)acc[e];
      pe[e] = expf(le - lm); ps += pe[e];
      sq += le * le;
    }
    float inv = 1.0f / ps;
    #pragma unroll
    for (int e = 0; e < NEXP; e++) atomicAdd(&bps[e], pe[e] * inv);
    atomicAdd(&bsq, sq);
  }
  __syncthreads();
  if (tid < NEXP) { atomicAdd(&psum[tid], bps[tid]); atomicAdd(&cnt1[tid], bc[tid]); }
  if (tid == 0) atomicAdd(sqsum, bsq);
}

// ---------------- grouped GEMM: gathered-A [rows from list] x Bt[e] ([N][K] bf16, k-contig) ----------------
// GEMM1: A=xb (row=aid>>1), K=1024, N=2048, out=H bf16 with bias+gelu
// GEMM2: A=H  (row=aid),    K=2048, N=1024, out=obuf f32 with bias
template<int K, int N, bool GELU, bool ROWSHIFT>
__global__ __launch_bounds__(256)
void k_gemm(const unsigned short* __restrict__ A, const unsigned short* __restrict__ Bt,
            const float* __restrict__ bias, void* __restrict__ Out,
            const int* __restrict__ elist, const int* __restrict__ ecnt) {
  __shared__ unsigned char lsA[128 * 128];   // 128 rows x 64 bf16 (128B), XOR-swizzled
  __shared__ unsigned char lsB[128 * 128];
  const int e = blockIdx.z, mt = blockIdx.y, nt = blockIdx.x;
  const int cnt = ecnt[e];
  const int m0 = mt * 128;
  if (m0 >= cnt) return;
  const int rv = min(128, cnt - m0);
  const int* lst = elist + e * CAP + m0;
  const int tid = threadIdx.x, wv = tid >> 6, lane = tid & 63;
  const int wm = wv >> 1, wn = wv & 1;
  const unsigned short* Be = Bt + (size_t)e * N * K;

  const int sr = lane >> 3;              // sub-row within 8-row chunk
  const int clin = (lane & 7) * 16;      // linear byte col inside row

  const unsigned short* agp[4];
  const unsigned short* bgp[4];
  int dstoff[4];
  #pragma unroll
  for (int li = 0; li < 4; li++) {
    int r = wv * 32 + li * 8 + sr;
    int rr = (r < rv) ? r : 0;           // clamp padded rows to a valid list entry
    int aid = lst[rr];
    int arow = ROWSHIFT ? (aid >> 1) : aid;
    int csrc = clin ^ ((r & 7) << 4);    // pre-swizzled global source (rule #21)
    agp[li] = A + (size_t)arow * K + (csrc >> 1);
    int n = nt * 128 + r;
    bgp[li] = Be + (size_t)n * K + (csrc >> 1);
    dstoff[li] = (wv * 32 + li * 8) * 128;
  }

  f32x4 acc[4][4];
  #pragma unroll
  for (int mi = 0; mi < 4; mi++)
    #pragma unroll
    for (int ni = 0; ni < 4; ni++)
      acc[mi][ni] = (f32x4){0.f, 0.f, 0.f, 0.f};

  for (int k0 = 0; k0 < K; k0 += 64) {
    #pragma unroll
    for (int li = 0; li < 4; li++) {
      gload16(agp[li] + k0, &lsA[dstoff[li]]);
      gload16(bgp[li] + k0, &lsB[dstoff[li]]);
    }
    __syncthreads();                     // drains vmcnt, publishes LDS
    #pragma unroll
    for (int ks = 0; ks < 2; ks++) {
      s16x8 af[4], bf[4];
      #pragma unroll
      for (int mi = 0; mi < 4; mi++) {
        int row = wm * 64 + mi * 16 + (lane & 15);
        int cb = (ks * 64 + (lane >> 4) * 16) ^ ((row & 7) << 4);
        af[mi] = *(const s16x8*)&lsA[row * 128 + cb];
      }
      #pragma unroll
      for (int ni = 0; ni < 4; ni++) {
        int row = wn * 64 + ni * 16 + (lane & 15);
        int cb = (ks * 64 + (lane >> 4) * 16) ^ ((row & 7) << 4);
        bf[ni] = *(const s16x8*)&lsB[row * 128 + cb];
      }
      #pragma unroll
      for (int mi = 0; mi < 4; mi++)
        #pragma unroll
        for (int ni = 0; ni < 4; ni++)
          acc[mi][ni] = __builtin_amdgcn_mfma_f32_16x16x32_bf16(af[mi], bf[ni], acc[mi][ni], 0, 0, 0);
    }
    __syncthreads();
  }

  // epilogue: C/D layout col=lane&15, row=4*(lane>>4)+reg (verified m89/m91)
  const int g4 = (lane >> 4) * 4, cn = lane & 15;
  #pragma unroll
  for (int mi = 0; mi < 4; mi++) {
    #pragma unroll
    for (int reg = 0; reg < 4; reg++) {
      int r = wm * 64 + mi * 16 + g4 + reg;
      if (r < rv) {
        int aid = lst[r];
        #pragma unroll
        for (int ni = 0; ni < 4; ni++) {
          int n = nt * 128 + wn * 64 + ni * 16 + cn;
          float v = acc[mi][ni][reg] + bias[(size_t)e * N + n];
          if constexpr (GELU) {
            v = 0.5f * v * (1.0f + erff(v * 0.70710678118654752f));  // exact gelu
            ((unsigned short*)Out)[(size_t)aid * N + n] = f2bf(v);
          } else {
            ((float*)Out)[(size_t)aid * N + n] = v;
          }
        }
      }
    }
  }
}

// ---------------- combine top-2 rows ----------------
__global__ void k_combine(const float* __restrict__ buf, const float* __restrict__ topw,
                          float* __restrict__ out) {
  int i = blockIdx.x * 256 + threadIdx.x;          // per float4, NTOK*DDIM/4 total
  int t = i >> 8, c = i & 255;                     // DDIM/4 = 256
  float w0 = topw[2*t], w1 = topw[2*t + 1];
  float4 a = ((const float4*)(buf + (size_t)(2*t) * DDIM))[c];
  float4 b = ((const float4*)(buf + (size_t)(2*t + 1) * DDIM))[c];
  float4 o;
  o.x = w0*a.x + w1*b.x; o.y = w0*a.y + w1*b.y;
  o.z = w0*a.z + w1*b.z; o.w = w0*a.w + w1*b.w;
  ((float4*)out)[i] = o;
}

__global__ void k_aux(const int* __restrict__ cnt1, const float* __restrict__ psum,
                      const float* __restrict__ sqsum, float* __restrict__ out) {
  if (threadIdx.x == 0 && blockIdx.x == 0) {
    float a = 0.f;
    for (int e = 0; e < NEXP; e++)
      a += ((float)cnt1[e] / (float)NTOK) * (psum[e] / (float)NTOK);
    out[(size_t)NTOK * DDIM] = (float)NEXP * a + (*sqsum) / (float)(NTOK * NEXP) * 1e-3f;
  }
}

extern "C" void kernel_launch(void* const* d_in, const int* in_sizes, int n_in,
                              void* d_out, int out_size, void* d_ws, size_t ws_size,
                              hipStream_t stream) {
  const float* x  = (const float*)d_in[0];
  const float* gw = (const float*)d_in[1];
  const float* w1 = (const float*)d_in[2];
  const float* b1 = (const float*)d_in[3];
  const float* w2 = (const float*)d_in[4];
  const float* b2 = (const float*)d_in[5];
  float* out = (float*)d_out;
  char* p = (char*)d_ws;

  // workspace layout (~136 MB)
  int*   ecnt  = (int*)p;                    // [8]
  int*   cnt1  = (int*)(p + 32);             // [8]
  float* psum  = (float*)(p + 64);           // [8]
  float* sqsum = (float*)(p + 96);           // [1]
  float* topw  = (float*)(p + 256);                            // 32 KB
  int*   elist = (int*)(p + 256 + 32768);                      // 128 KB
  unsigned short* xb  = (unsigned short*)(p + 256 + 32768 + 131072);   // 8 MB
  unsigned short* w1t = xb  + (size_t)NTOK * DDIM;                     // 32 MB  [E][F][D]
  unsigned short* w2t = w1t + (size_t)NEXP * DDIM * FDIM;              // 32 MB  [E][D][F]
  unsigned short* Hb  = w2t + (size_t)NEXP * DDIM * FDIM;              // 32 MB  [8192][F]
  float* obuf = (float*)(Hb + (size_t)NTOK * 2 * FDIM);                // 32 MB  [8192][D]

  hipMemsetAsync(p, 0, 128, stream);
  k_convert_x<<<NTOK * DDIM / 8 / 256, 256, 0, stream>>>(x, xb);
  k_transpose_cast<<<dim3(FDIM/32, DDIM/32, NEXP), dim3(32, 8), 0, stream>>>(w1, w1t, DDIM, FDIM);
  k_transpose_cast<<<dim3(DDIM/32, FDIM/32, NEXP), dim3(32, 8), 0, stream>>>(w2, w2t, FDIM, DDIM);
  k_router<<<NTOK / 4, 256, 0, stream>>>(x, gw, topw, elist, ecnt, cnt1, psum, sqsum);
  k_gemm<DDIM, FDIM, true,  true ><<<dim3(FDIM/128, CAP/128, NEXP), 256, 0, stream>>>(xb, w1t, b1, Hb, elist, ecnt);
  k_gemm<FDIM, DDIM, false, false><<<dim3(DDIM/128, CAP/128, NEXP), 256, 0, stream>>>(Hb, w2t, b2, obuf, elist, ecnt);
  k_combine<<<NTOK * DDIM / 4 / 256, 256, 0, stream>>>(obuf, topw, out);
  k_aux<<<1, 64, 0, stream>>>(cnt1, psum, sqsum, out);
}

// Round 2
// 290.527 us; speedup vs baseline: 1.2459x; 1.2459x over previous
//
#include <hip/hip_runtime.h>
#include <hip/hip_bf16.h>

#define NTOK 4096   // B*T
#define DDIM 1024
#define NEXP 8
#define FDIM 2048
#define CAP  4096   // max assignments per expert
#define RTOK 16     // tokens per router block

typedef float f32x4 __attribute__((ext_vector_type(4)));
typedef short s16x8 __attribute__((ext_vector_type(8)));

__device__ __forceinline__ unsigned short f2bf(float f) {
  unsigned int u = __float_as_uint(f);
  unsigned int r = u + 0x7fffu + ((u >> 16) & 1u);
  return (unsigned short)(r >> 16);
}

__device__ __forceinline__ void gload16(const void* g, void* l) {
  __builtin_amdgcn_global_load_lds(
      (__attribute__((address_space(1))) unsigned int*)(g),
      (__attribute__((address_space(3))) unsigned int*)(l), 16, 0, 0);
}

// ---------------- convert x fp32 -> bf16 ----------------
__global__ void k_convert_x(const float* __restrict__ x, unsigned short* __restrict__ xb) {
  int i = blockIdx.x * 256 + threadIdx.x;          // one thread per 8 elems
  const float4* x4 = (const float4*)x;
  float4 a = x4[2*i], b = x4[2*i+1];
  s16x8 o;
  o[0]=(short)f2bf(a.x); o[1]=(short)f2bf(a.y); o[2]=(short)f2bf(a.z); o[3]=(short)f2bf(a.w);
  o[4]=(short)f2bf(b.x); o[5]=(short)f2bf(b.y); o[6]=(short)f2bf(b.z); o[7]=(short)f2bf(b.w);
  ((s16x8*)xb)[i] = o;
}

// ---------------- transpose+cast weights: src [E][R][C] f32 -> dst [E][C][R] bf16 ----------------
__global__ void k_transpose_cast(const float* __restrict__ src, unsigned short* __restrict__ dst,
                                 int R, int C) {
  __shared__ float tile[32][33];
  int e = blockIdx.z;
  int c0 = blockIdx.x * 32, r0 = blockIdx.y * 32;
  const float* s = src + (size_t)e * R * C;
  unsigned short* d = dst + (size_t)e * R * C;
  int tx = threadIdx.x, ty = threadIdx.y;          // 32 x 8
  #pragma unroll
  for (int i = 0; i < 4; i++)
    tile[ty + i*8][tx] = s[(size_t)(r0 + ty + i*8) * C + (c0 + tx)];
  __syncthreads();
  #pragma unroll
  for (int i = 0; i < 4; i++)
    d[(size_t)(c0 + ty + i*8) * R + (r0 + tx)] = f2bf(tile[tx][ty + i*8]);
}

// ---------------- router v2: LDS-tiled, thread=(token,expert), fp64 accum ----------------
__global__ __launch_bounds__(128)
void k_router(const float* __restrict__ x, const float* __restrict__ gw,
              float* __restrict__ topw, int* __restrict__ elist,
              int* __restrict__ ecnt, int* __restrict__ cnt1,
              float* __restrict__ psum, float* __restrict__ sqsum) {
  __shared__ float gwt[NEXP][DDIM + 4];   // gw transposed [e][d], pad 4 -> conflict-free b128
  __shared__ float xs[RTOK][264];         // x chunk [tok][256 cols], pad 8 -> <=2-way
  __shared__ double lgd[RTOK][NEXP];
  __shared__ float bps[NEXP];
  __shared__ int bc[NEXP];
  __shared__ float bsq;
  const int tid = threadIdx.x;
  const int tok0 = blockIdx.x * RTOK;

  // stage gw transposed: gw[d*8+e] -> gwt[e][d]  (coalesced global read)
  for (int i = tid; i < DDIM * NEXP; i += 128) {
    int d = i >> 3, e = i & 7;
    gwt[e][d] = gw[i];
  }
  if (tid < NEXP) { bps[tid] = 0.f; bc[tid] = 0; }
  if (tid == 0) bsq = 0.f;

  const int t = tid >> 3, e = tid & 7;    // token-in-block, expert
  double a0 = 0.0, a1 = 0.0, a2 = 0.0, a3 = 0.0;
  for (int c = 0; c < DDIM; c += 256) {
    __syncthreads();
    // load xs chunk [16][256] coalesced (float4)
    for (int i = tid; i < RTOK * 64; i += 128) {
      int r = i >> 6, c4 = i & 63;
      float4 v = *(const float4*)(x + (size_t)(tok0 + r) * DDIM + c + c4 * 4);
      *(float4*)&xs[r][c4 * 4] = v;
    }
    __syncthreads();
    #pragma unroll 8
    for (int d4 = 0; d4 < 64; d4++) {
      float4 xv = *(const float4*)&xs[t][d4 * 4];
      float4 gv = *(const float4*)&gwt[e][c + d4 * 4];
      a0 += (double)xv.x * (double)gv.x;
      a1 += (double)xv.y * (double)gv.y;
      a2 += (double)xv.z * (double)gv.z;
      a3 += (double)xv.w * (double)gv.w;
    }
  }
  lgd[t][e] = (a0 + a1) + (a2 + a3);
  __syncthreads();

  if (tid < RTOK) {
    int tok = tok0 + tid;
    double acc[NEXP];
    #pragma unroll
    for (int k = 0; k < NEXP; k++) acc[k] = lgd[tid][k];
    int i0 = 0; double v0 = acc[0];
    #pragma unroll
    for (int k = 1; k < NEXP; k++) if (acc[k] > v0) { v0 = acc[k]; i0 = k; }
    int i1 = (i0 == 0) ? 1 : 0; double v1 = acc[i1];
    #pragma unroll
    for (int k = 0; k < NEXP; k++) if (k != i0 && acc[k] > v1) { v1 = acc[k]; i1 = k; }
    float w0 = 1.0f / (1.0f + expf((float)(v1 - v0)));   // softmax([v0,v1])[0]
    topw[2*tok] = w0; topw[2*tok + 1] = 1.0f - w0;
    int s0 = atomicAdd(&ecnt[i0], 1); elist[i0*CAP + s0] = 2*tok;
    int s1 = atomicAdd(&ecnt[i1], 1); elist[i1*CAP + s1] = 2*tok + 1;
    atomicAdd(&bc[i0], 1);
    float lm = (float)acc[0];
    #pragma unroll
    for (int k = 1; k < NEXP; k++) lm = fmaxf(lm, (float)acc[k]);
    float pe[NEXP], ps = 0.f, sq = 0.f;
    #pragma unroll
    for (int k = 0; k < NEXP; k++) {
      float le = (float)acc[k];
      pe[k] = expf(le - lm); ps += pe[k];
      sq += le * le;
    }
    float inv = 1.0f / ps;
    #pragma unroll
    for (int k = 0; k < NEXP; k++) atomicAdd(&bps[k], pe[k] * inv);
    atomicAdd(&bsq, sq);
  }
  __syncthreads();
  if (tid < NEXP) { atomicAdd(&psum[tid], bps[tid]); atomicAdd(&cnt1[tid], bc[tid]); }
  if (tid == 0) atomicAdd(sqsum, bsq);
}

// ---------------- grouped GEMM: gathered-A [rows from list] x Bt[e] ([N][K] bf16, k-contig) ----------------
// GEMM1: A=xb (row=aid>>1), K=1024, N=2048, out=H bf16 with bias+gelu
// GEMM2: A=H  (row=aid),    K=2048, N=1024, out=obuf f32 with bias
template<int K, int N, bool GELU, bool ROWSHIFT>
__global__ __launch_bounds__(256)
void k_gemm(const unsigned short* __restrict__ A, const unsigned short* __restrict__ Bt,
            const float* __restrict__ bias, void* __restrict__ Out,
            const int* __restrict__ elist, const int* __restrict__ ecnt) {
  __shared__ unsigned char lsA[128 * 128];   // 128 rows x 64 bf16 (128B), XOR-swizzled
  __shared__ unsigned char lsB[128 * 128];
  const int e = blockIdx.z, mt = blockIdx.y, nt = blockIdx.x;
  const int cnt = ecnt[e];
  const int m0 = mt * 128;
  if (m0 >= cnt) return;
  const int rv = min(128, cnt - m0);
  const int* lst = elist + e * CAP + m0;
  const int tid = threadIdx.x, wv = tid >> 6, lane = tid & 63;
  const int wm = wv >> 1, wn = wv & 1;
  const unsigned short* Be = Bt + (size_t)e * N * K;

  const int sr = lane >> 3;              // sub-row within 8-row chunk
  const int clin = (lane & 7) * 16;      // linear byte col inside row

  const unsigned short* agp[4];
  const unsigned short* bgp[4];
  int dstoff[4];
  #pragma unroll
  for (int li = 0; li < 4; li++) {
    int r = wv * 32 + li * 8 + sr;
    int rr = (r < rv) ? r : 0;           // clamp padded rows to a valid list entry
    int aid = lst[rr];
    int arow = ROWSHIFT ? (aid >> 1) : aid;
    int csrc = clin ^ ((r & 7) << 4);    // pre-swizzled global source (rule #21)
    agp[li] = A + (size_t)arow * K + (csrc >> 1);
    int n = nt * 128 + r;
    bgp[li] = Be + (size_t)n * K + (csrc >> 1);
    dstoff[li] = (wv * 32 + li * 8) * 128;
  }

  f32x4 acc[4][4];
  #pragma unroll
  for (int mi = 0; mi < 4; mi++)
    #pragma unroll
    for (int ni = 0; ni < 4; ni++)
      acc[mi][ni] = (f32x4){0.f, 0.f, 0.f, 0.f};

  for (int k0 = 0; k0 < K; k0 += 64) {
    #pragma unroll
    for (int li = 0; li < 4; li++) {
      gload16(agp[li] + k0, &lsA[dstoff[li]]);
      gload16(bgp[li] + k0, &lsB[dstoff[li]]);
    }
    __syncthreads();                     // drains vmcnt, publishes LDS
    #pragma unroll
    for (int ks = 0; ks < 2; ks++) {
      s16x8 af[4], bf[4];
      #pragma unroll
      for (int mi = 0; mi < 4; mi++) {
        int row = wm * 64 + mi * 16 + (lane & 15);
        int cb = (ks * 64 + (lane >> 4) * 16) ^ ((row & 7) << 4);
        af[mi] = *(const s16x8*)&lsA[row * 128 + cb];
      }
      #pragma unroll
      for (int ni = 0; ni < 4; ni++) {
        int row = wn * 64 + ni * 16 + (lane & 15);
        int cb = (ks * 64 + (lane >> 4) * 16) ^ ((row & 7) << 4);
        bf[ni] = *(const s16x8*)&lsB[row * 128 + cb];
      }
      #pragma unroll
      for (int mi = 0; mi < 4; mi++)
        #pragma unroll
        for (int ni = 0; ni < 4; ni++)
          acc[mi][ni] = __builtin_amdgcn_mfma_f32_16x16x32_bf16(af[mi], bf[ni], acc[mi][ni], 0, 0, 0);
    }
    __syncthreads();
  }

  // epilogue: C/D layout col=lane&15, row=4*(lane>>4)+reg (verified m89/m91)
  const int g4 = (lane >> 4) * 4, cn = lane & 15;
  #pragma unroll
  for (int mi = 0; mi < 4; mi++) {
    #pragma unroll
    for (int reg = 0; reg < 4; reg++) {
      int r = wm * 64 + mi * 16 + g4 + reg;
      if (r < rv) {
        int aid = lst[r];
        #pragma unroll
        for (int ni = 0; ni < 4; ni++) {
          int n = nt * 128 + wn * 64 + ni * 16 + cn;
          float v = acc[mi][ni][reg] + bias[(size_t)e * N + n];
          if constexpr (GELU) {
            v = 0.5f * v * (1.0f + erff(v * 0.70710678118654752f));  // exact gelu
            ((unsigned short*)Out)[(size_t)aid * N + n] = f2bf(v);
          } else {
            ((float*)Out)[(size_t)aid * N + n] = v;
          }
        }
      }
    }
  }
}

// ---------------- combine top-2 rows ----------------
__global__ void k_combine(const float* __restrict__ buf, const float* __restrict__ topw,
                          float* __restrict__ out) {
  int i = blockIdx.x * 256 + threadIdx.x;          // per float4, NTOK*DDIM/4 total
  int t = i >> 8, c = i & 255;                     // DDIM/4 = 256
  float w0 = topw[2*t], w1 = topw[2*t + 1];
  float4 a = ((const float4*)(buf + (size_t)(2*t) * DDIM))[c];
  float4 b = ((const float4*)(buf + (size_t)(2*t + 1) * DDIM))[c];
  float4 o;
  o.x = w0*a.x + w1*b.x; o.y = w0*a.y + w1*b.y;
  o.z = w0*a.z + w1*b.z; o.w = w0*a.w + w1*b.w;
  ((float4*)out)[i] = o;
}

__global__ void k_aux(const int* __restrict__ cnt1, const float* __restrict__ psum,
                      const float* __restrict__ sqsum, float* __restrict__ out) {
  if (threadIdx.x == 0 && blockIdx.x == 0) {
    float a = 0.f;
    for (int e = 0; e < NEXP; e++)
      a += ((float)cnt1[e] / (float)NTOK) * (psum[e] / (float)NTOK);
    out[(size_t)NTOK * DDIM] = (float)NEXP * a + (*sqsum) / (float)(NTOK * NEXP) * 1e-3f;
  }
}

extern "C" void kernel_launch(void* const* d_in, const int* in_sizes, int n_in,
                              void* d_out, int out_size, void* d_ws, size_t ws_size,
                              hipStream_t stream) {
  const float* x  = (const float*)d_in[0];
  const float* gw = (const float*)d_in[1];
  const float* w1 = (const float*)d_in[2];
  const float* b1 = (const float*)d_in[3];
  const float* w2 = (const float*)d_in[4];
  const float* b2 = (const float*)d_in[5];
  float* out = (float*)d_out;
  char* p = (char*)d_ws;

  // workspace layout (~136 MB)
  int*   ecnt  = (int*)p;                    // [8]
  int*   cnt1  = (int*)(p + 32);             // [8]
  float* psum  = (float*)(p + 64);           // [8]
  float* sqsum = (float*)(p + 96);           // [1]
  float* topw  = (float*)(p + 256);                            // 32 KB
  int*   elist = (int*)(p + 256 + 32768);                      // 128 KB
  unsigned short* xb  = (unsigned short*)(p + 256 + 32768 + 131072);   // 8 MB
  unsigned short* w1t = xb  + (size_t)NTOK * DDIM;                     // 32 MB  [E][F][D]
  unsigned short* w2t = w1t + (size_t)NEXP * DDIM * FDIM;              // 32 MB  [E][D][F]
  unsigned short* Hb  = w2t + (size_t)NEXP * DDIM * FDIM;              // 32 MB  [8192][F]
  float* obuf = (float*)(Hb + (size_t)NTOK * 2 * FDIM);                // 32 MB  [8192][D]

  hipMemsetAsync(p, 0, 128, stream);
  k_convert_x<<<NTOK * DDIM / 8 / 256, 256, 0, stream>>>(x, xb);
  k_transpose_cast<<<dim3(FDIM/32, DDIM/32, NEXP), dim3(32, 8), 0, stream>>>(w1, w1t, DDIM, FDIM);
  k_transpose_cast<<<dim3(DDIM/32, FDIM/32, NEXP), dim3(32, 8), 0, stream>>>(w2, w2t, FDIM, DDIM);
  k_router<<<NTOK / RTOK, 128, 0, stream>>>(x, gw, topw, elist, ecnt, cnt1, psum, sqsum);
  k_gemm<DDIM, FDIM, true,  true ><<<dim3(FDIM/128, CAP/128, NEXP), 256, 0, stream>>>(xb, w1t, b1, Hb, elist, ecnt);
  k_gemm<FDIM, DDIM, false, false><<<dim3(DDIM/128, CAP/128, NEXP), 256, 0, stream>>>(Hb, w2t, b2, obuf, elist, ecnt);
  k_combine<<<NTOK * DDIM / 4 / 256, 256, 0, stream>>>(obuf, topw, out);
  k_aux<<<1, 64, 0, stream>>>(cnt1, psum, sqsum, out);
}